// Round 1
// baseline (866.421 us; speedup 1.0000x reference)
//
#include <hip/hip_runtime.h>
#include <hip/hip_bf16.h>
#include <math.h>

#define NTOK 8192
#define DIN  4096
#define HG   256
#define NE   64

// ---------------------------------------------------------------------------
// Kernel 1: h_t[HG][NTOK] = gelu(x @ w1^T + b1)^T   (transposed for coalesced
// stores and coalesced column reads in the gating kernel)
//
// lane = m (row of x). w1 values are wave-uniform -> SGPR operand of v_fmac.
// x tile staged in LDS transposed [k][m] (stride 66 pad -> conflict-free).
// WG = 256 threads = 4 waves; wave w covers 16 n. BN=64 -> grid 128*4 = 512.
// ---------------------------------------------------------------------------
__global__ __launch_bounds__(256, 2) void gemm1_gelu_kernel(
    const float* __restrict__ x, const float* __restrict__ w1,
    const float* __restrict__ b1, float* __restrict__ h_t)
{
    const int bid  = blockIdx.x;
    const int mb   = bid & 127;      // 128 m-blocks (consecutive bids share nb)
    const int nb   = bid >> 7;       // 4 n-blocks
    const int t    = threadIdx.x;
    const int lane = t & 63;
    const int wid  = __builtin_amdgcn_readfirstlane(t >> 6);
    const int m0   = mb * 64;
    const int nbase = nb * 64 + wid * 16;

    __shared__ float a_lds[2][64][66];   // [buf][k][m], pad 66 -> 2-way free

    // staging: thread t loads row mr, 4 x float4 at k offsets (t&3)*4 + {0,16,32,48}
    const int mr = t >> 2;
    const int kq = (t & 3) * 4;
    const float* xrow = x + (size_t)(m0 + mr) * DIN;

    float acc[16];
#pragma unroll
    for (int i = 0; i < 16; ++i) acc[i] = 0.f;

    float4 p0 = *(const float4*)(xrow + kq);
    float4 p1 = *(const float4*)(xrow + 16 + kq);
    float4 p2 = *(const float4*)(xrow + 32 + kq);
    float4 p3 = *(const float4*)(xrow + 48 + kq);

#define STASH(BUF, KK, V)                                                    \
    a_lds[BUF][(KK) + 0][mr] = (V).x;  a_lds[BUF][(KK) + 1][mr] = (V).y;     \
    a_lds[BUF][(KK) + 2][mr] = (V).z;  a_lds[BUF][(KK) + 3][mr] = (V).w;

    STASH(0, kq, p0) STASH(0, 16 + kq, p1) STASH(0, 32 + kq, p2) STASH(0, 48 + kq, p3)
    __syncthreads();

    int cur = 0;
#pragma unroll 1
    for (int tile = 0; tile < DIN / 64; ++tile) {
        // prefetch next tile into registers (overlaps with compute below)
        if (tile < DIN / 64 - 1) {
            const float* src = xrow + (tile + 1) * 64;
            p0 = *(const float4*)(src + kq);
            p1 = *(const float4*)(src + 16 + kq);
            p2 = *(const float4*)(src + 32 + kq);
            p3 = *(const float4*)(src + 48 + kq);
        }
        // two-level accumulation for fp32 fidelity (tile-local acc, folded once)
        float tacc[16];
#pragma unroll
        for (int i = 0; i < 16; ++i) tacc[i] = 0.f;
        const int k0 = tile * 64;
#pragma unroll
        for (int kc = 0; kc < 64; kc += 16) {
            float a[16];
#pragma unroll
            for (int j = 0; j < 16; ++j) a[j] = a_lds[cur][kc + j][lane];
#pragma unroll
            for (int n = 0; n < 16; ++n) {
                const float* wr = w1 + (size_t)(nbase + n) * DIN + (k0 + kc); // uniform -> s_load
#pragma unroll
                for (int j = 0; j < 16; ++j)
                    tacc[n] = fmaf(wr[j], a[j], tacc[n]);
            }
        }
#pragma unroll
        for (int i = 0; i < 16; ++i) acc[i] += tacc[i];

        __syncthreads();
        if (tile < DIN / 64 - 1) {
            const int nxt = cur ^ 1;
            STASH(nxt, kq, p0) STASH(nxt, 16 + kq, p1)
            STASH(nxt, 32 + kq, p2) STASH(nxt, 48 + kq, p3)
        }
        __syncthreads();
        cur ^= 1;
    }
#undef STASH

    // epilogue: bias + exact GELU, coalesced transposed store
#pragma unroll
    for (int n = 0; n < 16; ++n) {
        float v = acc[n] + b1[nbase + n];
        float g = 0.5f * v * (1.0f + erff(v * 0.70710678118654752440f));
        h_t[(size_t)(nbase + n) * NTOK + m0 + lane] = g;
    }
}

// ---------------------------------------------------------------------------
// Kernel 2: logits = h @ w2^T, softmax over 64 experts, top-2 (stable), writes
// d_out = [ indices(as float) N*2 | gates N*2 | probs N*64 ]
// lane = row; wave w computes 16 experts; logits exchanged through padded LDS;
// wave 0 does per-lane (per-row) softmax + top-2 entirely in registers.
// ---------------------------------------------------------------------------
__global__ __launch_bounds__(256, 2) void gating_kernel(
    const float* __restrict__ h_t, const float* __restrict__ w2,
    float* __restrict__ out)
{
    const int t    = threadIdx.x;
    const int lane = t & 63;
    const int wid  = __builtin_amdgcn_readfirstlane(t >> 6);
    const int row0 = blockIdx.x * 64;
    const int row  = row0 + lane;
    const int e0   = wid * 16;

    __shared__ float lg[NE][65];

    float acc[16];
#pragma unroll
    for (int i = 0; i < 16; ++i) acc[i] = 0.f;

#pragma unroll 1
    for (int kc = 0; kc < HG; kc += 16) {
        float a[16];
#pragma unroll
        for (int j = 0; j < 16; ++j) a[j] = h_t[(size_t)(kc + j) * NTOK + row]; // coalesced
#pragma unroll
        for (int n = 0; n < 16; ++n) {
            const float* wr = w2 + (e0 + n) * HG + kc;   // uniform -> s_load
#pragma unroll
            for (int j = 0; j < 16; ++j)
                acc[n] = fmaf(wr[j], a[j], acc[n]);
        }
    }
#pragma unroll
    for (int n = 0; n < 16; ++n) lg[e0 + n][lane] = acc[n];
    __syncthreads();

    if (wid == 0) {
        float l[NE];
#pragma unroll
        for (int e = 0; e < NE; ++e) l[e] = lg[e][lane];

        float mx = l[0];
#pragma unroll
        for (int e = 1; e < NE; ++e) mx = fmaxf(mx, l[e]);

        float s = 0.f;
#pragma unroll
        for (int e = 0; e < NE; ++e) { float p = expf(l[e] - mx); l[e] = p; s += p; }
        const float inv = 1.0f / s;
#pragma unroll
        for (int e = 0; e < NE; ++e) l[e] *= inv;

        // stable top-2: strict '>' => lowest index wins ties (matches lax.top_k)
        float v1 = -1.0f, v2 = -2.0f;
        int   i1 = 0,     i2 = 0;
#pragma unroll
        for (int e = 0; e < NE; ++e) {
            const float p  = l[e];
            const bool  g1 = p > v1;
            const bool  g2 = p > v2;
            const float nv2 = g1 ? v1 : (g2 ? p : v2);
            const int   ni2 = g1 ? i1 : (g2 ? e : i2);
            v1 = g1 ? p : v1;
            i1 = g1 ? e : i1;
            v2 = nv2;
            i2 = ni2;
        }

        float* out_idx  = out;
        float* out_gate = out + 2 * NTOK;
        float* out_prob = out + 4 * NTOK;
        out_idx[2 * row + 0]  = (float)i1;
        out_idx[2 * row + 1]  = (float)i2;
        out_gate[2 * row + 0] = v1;
        out_gate[2 * row + 1] = v2;

        float* pr = out_prob + (size_t)row * NE;
#pragma unroll
        for (int e = 0; e < NE; e += 4) {
            float4 v = make_float4(l[e], l[e + 1], l[e + 2], l[e + 3]);
            *(float4*)(pr + e) = v;
        }
    }
}

extern "C" void kernel_launch(void* const* d_in, const int* in_sizes, int n_in,
                              void* d_out, int out_size, void* d_ws, size_t ws_size,
                              hipStream_t stream) {
    const float* x  = (const float*)d_in[0];
    const float* w1 = (const float*)d_in[1];
    const float* b1 = (const float*)d_in[2];
    const float* w2 = (const float*)d_in[3];
    float* out = (float*)d_out;
    float* h_t = (float*)d_ws;   // HG * NTOK fp32 = 8 MB scratch

    gemm1_gelu_kernel<<<512, 256, 0, stream>>>(x, w1, b1, h_t);
    gating_kernel<<<128, 256, 0, stream>>>(h_t, w2, out);
}